// Round 1
// baseline (83.105 us; speedup 1.0000x reference)
//
#include <hip/hip_runtime.h>
#include <math.h>

// Problem constants (B=8, L_IN=4096, D=256, T_OUT=1024)
#define BB   8
#define LL   4096
#define DD   256
#define TT   1024
#define EPSV 1e-12f

// ---------------------------------------------------------------------------
// Kernel 1 (1 block): per-batch valid length Lb via 64-ary prefix search,
// written to workspace. Also fills the out_mask region with 1.0f using
// coalesced float4 stores, so the hot kernel performs ZERO scattered dword
// stores (previously 8192 lane-0 stores partially writing shared 64B lines
// from different XCDs).
// ---------------------------------------------------------------------------
__global__ __launch_bounds__(256) void changelen_prep(const void* __restrict__ mask,
                                                      int* __restrict__ lb,
                                                      float* __restrict__ out) {
    const int wave = threadIdx.x >> 6;   // 0..3
    const int lane = threadIdx.x & 63;
    const int* mi32 = (const int*)mask;
    const unsigned char* mu8 = (const unsigned char*)mask;
    const bool is_i32 = (mi32[0] == 1);  // layout probe (mask[0][0] is true)

    for (int b = wave; b < BB; b += 4) {
        bool p1;
        if (is_i32) p1 = (mi32[(size_t)b * LL + lane * 64 + 63] != 0);
        else        p1 = (mu8 [(size_t)b * LL + lane * 64 + 63] != 0);
        const int n1 = __popcll(__ballot(p1));       // floor(Lb/64)
        int Lbi;
        if (n1 == 64) {
            Lbi = LL;                                // all-true row
        } else {
            const int base = n1 << 6;
            bool p2;
            if (is_i32) p2 = (mi32[(size_t)b * LL + base + lane] != 0);
            else        p2 = (mu8 [(size_t)b * LL + base + lane] != 0);
            Lbi = base + __popcll(__ballot(p2));
        }
        if (lane == 0) lb[b] = Lbi;
    }

    // out_mask = 1.0f : B*T floats at float-offset B*T*D (16B aligned)
    const float4 ones = {1.f, 1.f, 1.f, 1.f};
    float4* m4 = (float4*)(out + (size_t)BB * TT * DD);
    #pragma unroll
    for (int i = 0; i < (BB * TT) / (4 * 256); ++i)   // 8 iters
        m4[i * 256 + threadIdx.x] = ones;
}

// ---------------------------------------------------------------------------
// Kernel 2: one WAVE per (b,t) bin, 4 bins per 256-thread block. Lane owns 4
// channels via float4 (64 lanes x 16 B = 1 KB contiguous row transaction).
//
// Lb comes from workspace -> prologue is ONE uniform L2-hit load instead of
// two dependent scattered mask probes + ballots.
//
// Support size cnt = ceil(end)-floor(start) is wave-uniform (2..5). Rows
// 0..2 load unconditionally (row 2 clamped in-buffer when cnt==2 at the
// array end; its weight is 0). Rows 3/4 load under wave-uniform branches;
// the FMA section stays straight-line with zero-init vectors for skipped
// rows (their weights are exactly 0 anyway).
// All weight math exact in f32 (t*Lb < 2^22); Wsum == step exactly.
// ---------------------------------------------------------------------------
__global__ __launch_bounds__(256) void changelen_main(const float* __restrict__ x,
                                                      const int* __restrict__ lb,
                                                      float* __restrict__ out) {
    const int wave = threadIdx.x >> 6;
    const int lane = threadIdx.x & 63;
    const int bt   = (blockIdx.x << 2) + wave;   // 0 .. B*T-1
    const int b    = blockIdx.x >> 8;            // block-uniform (1024 % 4 == 0)
    const int t    = bt & (TT - 1);

    const int Lbi = lb[b];                       // uniform, L2-hit

    // ---- bin geometry (exact in f32) ----
    const float Lb    = (float)Lbi;
    const float step  = Lb * (1.0f / (float)TT);
    const float start = (float)t * step;
    const float end   = start + step;
    const float s_f   = floorf(start);
    const float e_f   = ceilf(end);
    const int   s     = (int)s_f;
    const int   cnt   = (int)e_f - s;            // wave-uniform, 2..5
    const float inv_cnt = 1.0f / fmaxf(e_f - s_f, 1.0f);

    // ---- row loads ----
    const float* xb = x + (size_t)b * LL * DD;
    const float4* r0 = (const float4*)(xb + (size_t)s * DD);

    float4 v0 = r0[lane];
    float4 v1 = r0[64 + lane];
    const int o2 = (s + 2 < LL) ? 128 : 64;      // keep the w=0 row in-buffer
    float4 v2 = r0[o2 + lane];
    float4 v3 = {0.f, 0.f, 0.f, 0.f};
    float4 v4 = {0.f, 0.f, 0.f, 0.f};
    if (cnt > 3) v3 = r0[192 + lane];            // row s+3 < e <= Lb : valid
    if (cnt > 4) v4 = r0[256 + lane];            // row s+4 < e <= Lb : valid

    // ---- straight-line accumulate ----
    float4 sumA = {0.f, 0.f, 0.f, 0.f};
    float4 sw   = {0.f, 0.f, 0.f, 0.f};
    float4 sw2  = {0.f, 0.f, 0.f, 0.f};

#define ACC(K, V)                                                              \
    {                                                                          \
        const float fi = (float)(s + (K));                                     \
        float w = fminf(fi + 1.0f, end) - fmaxf(fi, start);                    \
        w = fmaxf(w, 0.0f);                          /* 0 for rows >= e */     \
        const float am = ((K) < cnt) ? inv_cnt : 0.0f;                         \
        sumA.x = fmaf(am, (V).x, sumA.x); sumA.y = fmaf(am, (V).y, sumA.y);    \
        sumA.z = fmaf(am, (V).z, sumA.z); sumA.w = fmaf(am, (V).w, sumA.w);    \
        sw.x = fmaf(w, (V).x, sw.x); sw.y = fmaf(w, (V).y, sw.y);              \
        sw.z = fmaf(w, (V).z, sw.z); sw.w = fmaf(w, (V).w, sw.w);              \
        sw2.x = fmaf(w, (V).x * (V).x, sw2.x);                                 \
        sw2.y = fmaf(w, (V).y * (V).y, sw2.y);                                 \
        sw2.z = fmaf(w, (V).z * (V).z, sw2.z);                                 \
        sw2.w = fmaf(w, (V).w * (V).w, sw2.w);                                 \
    }

    ACC(0, v0)
    ACC(1, v1)
    ACC(2, v2)
    ACC(3, v3)
    ACC(4, v4)
#undef ACC

    // ---- epilogue: std; vector stores ----
    float4 stdv;
    {
        const float inv_s = 1.0f / step;         // Wsum == step exactly
        const float mx = sw.x * inv_s, my = sw.y * inv_s, mz = sw.z * inv_s, mw = sw.w * inv_s;
        const float qx = sw2.x * inv_s, qy = sw2.y * inv_s, qz = sw2.z * inv_s, qw = sw2.w * inv_s;
        stdv.x = sqrtf(fmaxf(qx - mx * mx, EPSV));
        stdv.y = sqrtf(fmaxf(qy - my * my, EPSV));
        stdv.z = sqrtf(fmaxf(qz - mz * mz, EPSV));
        stdv.w = sqrtf(fmaxf(qw - mw * mw, EPSV));
    }

    float4* out4 = (float4*)out;
    const size_t o4 = (size_t)bt * (DD / 4) + (size_t)lane;            // padded_out
    const size_t std_base4 = ((size_t)BB * TT * DD + (size_t)BB * TT) / 4;
    out4[o4] = sumA;
    out4[std_base4 + o4] = stdv;
}

extern "C" void kernel_launch(void* const* d_in, const int* in_sizes, int n_in,
                              void* d_out, int out_size, void* d_ws, size_t ws_size,
                              hipStream_t stream) {
    const float* x    = (const float*)d_in[0];
    const void*  mask = d_in[1];
    // d_in[2] = finallength (always 1024, hard-coded as TT)
    float* out = (float*)d_out;
    int*   lb  = (int*)d_ws;

    changelen_prep<<<1, 256, 0, stream>>>(mask, lb, out);
    changelen_main<<<(BB * TT) / 4, 256, 0, stream>>>(x, lb, out);
}